// Round 1
// baseline (823.054 us; speedup 1.0000x reference)
//
#include <hip/hip_runtime.h>

constexpr int W = 128, H = 256, ITERS = 24, B = 256, K_IN = 784, NC = 10;
constexpr int HWT_S = 132;             // HWt row stride (wi dim 0..128, padded)
constexpr int S = 260;                 // LDS act row stride in floats
constexpr int LDS_WORDS = 130 * S;     // 33800 floats
constexpr int LDS_BYTES = LDS_WORDS * 4;  // 135200 B (<160 KiB)

// Module-scope scratch (rewritten fully on every kernel_launch; no cross-call state read)
__device__ float g_pre[B * H];
__device__ float g_HWt[H * HWT_S];     // [h][wi]  hwL(w,h)=HWt[h][w], hwR(w,h)=HWt[h][w+1]
__device__ float g_VWt[(H + 1) * W];   // [hc][w]  vwD(w,h)=VWt[h][w], vwU(w,h)=VWt[h+1][w]
__device__ float g_BSt[H * W];         // [h][w]   precomputed bias sum

__global__ void build_weights(const float* __restrict__ hw, const float* __restrict__ vw,
                              const float* __restrict__ hb, const float* __restrict__ vb) {
    int idx = blockIdx.x * blockDim.x + threadIdx.x;
    int nthr = gridDim.x * blockDim.x;
    // HWt[h][wi]: wi in 0..131; valid weight rows are wi=1..127 -> hw[wi-1][h]
    for (int i = idx; i < H * HWT_S; i += nthr) {
        int h = i / HWT_S, wi = i % HWT_S;
        g_HWt[i] = (wi >= 1 && wi <= W - 1) ? hw[(wi - 1) * H + h] : 0.f;
    }
    // VWt[hc][w]: hc in 0..256; valid hc=1..255 -> vw[w][hc-1]
    for (int i = idx; i < (H + 1) * W; i += nthr) {
        int hc = i / W, w = i % W;
        g_VWt[i] = (hc >= 1 && hc <= H - 1) ? vw[w * (H - 1) + (hc - 1)] : 0.f;
    }
    // BSt[h][w] = masked hbL + hbR + vbD + vbU
    for (int i = idx; i < H * W; i += nthr) {
        int h = i / W, w = i % W;
        float v = 0.f;
        if (w > 0)     v += hb[(w - 1) * H + h];
        if (w < W - 1) v += hb[w * H + h];
        if (h > 0)     v += vb[w * (H - 1) + (h - 1)];
        if (h < H - 1) v += vb[w * (H - 1) + h];
        g_BSt[i] = v;
    }
}

__global__ void pre_gemm(const float* __restrict__ x, const float* __restrict__ w_pre,
                         const float* __restrict__ b_pre) {
    int b = blockIdx.x, j = threadIdx.x;   // 256 x 256
    const float* xr = x + b * K_IN;
    float acc = b_pre[j];
#pragma unroll 8
    for (int k = 0; k < K_IN; ++k) acc += xr[k] * w_pre[k * H + j];
    g_pre[b * H + j] = acc;
}

__global__ __launch_bounds__(1024, 1) void grid_iter(const float* __restrict__ w_out,
                                                     const float* __restrict__ b_out,
                                                     float* __restrict__ out) {
    extern __shared__ float A[];   // [130][S], row r=w+1, col c=h+1; border stays 0
    const int tid = threadIdx.x, b = blockIdx.x;

    for (int i = tid; i < LDS_WORDS; i += 1024) A[i] = 0.f;
    __syncthreads();
    if (tid < H) A[1 * S + 1 + tid] = g_pre[b * H + tid];
    __syncthreads();

    const int w = tid & (W - 1);          // 0..127, lane-varying
    const int h0 = (tid >> 7) << 5;       // 0,32,...,224 (wave-uniform)
    const int r = w + 1;

    float* __restrict__ rowm = A + (r - 1) * S + h0;  // neighbor row w-1, col base h0
    float* __restrict__ row0 = A + r * S + h0;        // own row, col base h0 (c-1 at j=0)
    float* __restrict__ rowp = A + (r + 1) * S + h0;  // neighbor row w+1
    const float* __restrict__ hwl = g_HWt + h0 * HWT_S + w;
    const float* __restrict__ vwt = g_VWt + h0 * W + w;
    const float* __restrict__ bst = g_BSt + h0 * W + w;

    for (int it = 0; it < ITERS; ++it) {
        float nv[32];
#pragma unroll
        for (int j = 0; j < 32; ++j) {
            float aL = rowm[1 + j];          // act[w-1][h]
            float aR = rowp[1 + j];          // act[w+1][h]
            float aD = row0[j];              // act[w][h-1]
            float aU = row0[j + 2];          // act[w][h+1]
            float xv = bst[j * W]
                     + hwl[j * HWT_S]     * aL
                     + hwl[j * HWT_S + 1] * aR
                     + vwt[j * W]         * aD
                     + vwt[(j + 1) * W]   * aU;
            nv[j] = 1.f / (1.f + __expf(-xv));
        }
        __syncthreads();
#pragma unroll
        for (int j = 0; j < 32; ++j) row0[1 + j] = nv[j];
        __syncthreads();
    }

    // out[b][cls] = b_out[cls] + sum_h act[W-2][h] * w_out[h][cls];  row w=126 -> r=127
    if (tid < NC * 64) {
        const int cls = tid >> 6, lane = tid & 63;
        const float* arow = A + (W - 1) * S + 1;   // r = 127
        float p = 0.f;
#pragma unroll
        for (int h = lane; h < H; h += 64) p += arow[h] * w_out[h * NC + cls];
#pragma unroll
        for (int off = 32; off > 0; off >>= 1) p += __shfl_down(p, off, 64);
        if (lane == 0) out[b * NC + cls] = p + b_out[cls];
    }
}

extern "C" void kernel_launch(void* const* d_in, const int* in_sizes, int n_in,
                              void* d_out, int out_size, void* d_ws, size_t ws_size,
                              hipStream_t stream) {
    const float* x     = (const float*)d_in[0];
    const float* w_pre = (const float*)d_in[1];
    const float* b_pre = (const float*)d_in[2];
    const float* hw    = (const float*)d_in[3];
    const float* vw    = (const float*)d_in[4];
    const float* hb    = (const float*)d_in[5];
    const float* vb    = (const float*)d_in[6];
    const float* w_out = (const float*)d_in[7];
    const float* b_out = (const float*)d_in[8];
    float* out = (float*)d_out;

    (void)hipFuncSetAttribute((const void*)grid_iter,
                              hipFuncAttributeMaxDynamicSharedMemorySize, LDS_BYTES);

    hipLaunchKernelGGL(build_weights, dim3(128), dim3(256), 0, stream, hw, vw, hb, vb);
    hipLaunchKernelGGL(pre_gemm, dim3(B), dim3(H), 0, stream, x, w_pre, b_pre);
    hipLaunchKernelGGL(grid_iter, dim3(B), dim3(1024), LDS_BYTES, stream, w_out, b_out, out);
}

// Round 2
// 419.455 us; speedup vs baseline: 1.9622x; 1.9622x over previous
//
#include <hip/hip_runtime.h>
#include <hip/hip_fp16.h>

constexpr int W = 128, H = 256, ITERS = 24, B = 256, K_IN = 784, NC = 10;
constexpr int WPT = 72;    // packed fp16x2 weight words per thread

// Packed per-thread weights, [word][tid] for coalesced loads. Rebuilt every launch.
__device__ __half2 g_PK[WPT * 1024];
__device__ float g_pre[B * H];

// Per-thread cell mapping (identical in build_pack and grid_iter):
//   p = tid>>6 (wave), lane = tid&63; rows w = 8p..8p+7, cols h = 4*lane..4*lane+3.
// Word layout per thread t:
//   [0..31]  rw*4+j : half2(hwL, hwR) for cell (8p+rw, h0+j)
//   [32..55] 32+rw*3+k : half2(VD(h0+2k), VD(h0+2k+1))   VD(h)=aD coeff at col h
//   [56..71] 56+rw*2+k : half2(bias(h0+2k), bias(h0+2k+1))
__global__ void build_pack(const float* __restrict__ hw, const float* __restrict__ vw,
                           const float* __restrict__ hbp, const float* __restrict__ vbp) {
    const int t = threadIdx.x;           // single block of 1024
    const int p = t >> 6, lane = t & 63;
    const int w8 = p * 8, h0 = lane * 4;

    for (int rw = 0; rw < 8; ++rw) {
        const int w = w8 + rw;
        for (int j = 0; j < 4; ++j) {
            const int h = h0 + j;
            float L = (w >= 1)     ? hw[(w - 1) * H + h] : 0.f;   // coeff of act[w-1][h]
            float R = (w <= W - 2) ? hw[w * H + h]       : 0.f;   // coeff of act[w+1][h]
            g_PK[(rw * 4 + j) * 1024 + t] = __floats2half2_rn(L, R);
        }
        for (int k = 0; k < 3; ++k) {
            const int ha = h0 + 2 * k, hc = ha + 1;
            float v0 = (ha >= 1 && ha <= H - 1) ? vw[w * (H - 1) + ha - 1] : 0.f;
            float v1 = (hc >= 1 && hc <= H - 1) ? vw[w * (H - 1) + hc - 1] : 0.f;
            g_PK[(32 + rw * 3 + k) * 1024 + t] = __floats2half2_rn(v0, v1);
        }
        for (int k = 0; k < 2; ++k) {
            float s[2];
            for (int m = 0; m < 2; ++m) {
                const int h = h0 + 2 * k + m;
                float v = 0.f;
                if (w >= 1)     v += hbp[(w - 1) * H + h];
                if (w <= W - 2) v += hbp[w * H + h];
                if (h >= 1)     v += vbp[w * (H - 1) + h - 1];
                if (h <= H - 2) v += vbp[w * (H - 1) + h];
                s[m] = v;
            }
            g_PK[(56 + rw * 2 + k) * 1024 + t] = __floats2half2_rn(s[0], s[1]);
        }
    }
}

__global__ void pre_gemm(const float* __restrict__ x, const float* __restrict__ w_pre,
                         const float* __restrict__ b_pre) {
    int b = blockIdx.x, j = threadIdx.x;   // 256 x 256
    const float* xr = x + b * K_IN;
    float acc = b_pre[j];
#pragma unroll 8
    for (int k = 0; k < K_IN; ++k) acc += xr[k] * w_pre[k * H + j];
    g_pre[b * H + j] = acc;
}

__global__ __launch_bounds__(1024, 1) void grid_iter(const float* __restrict__ w_out,
                                                     const float* __restrict__ b_out,
                                                     float* __restrict__ out) {
    // Publish buffer: only the 2 boundary w-rows per wave cross LDS. Double-buffered.
    // Slot 2p = row 8p (old), slot 2p+1 = row 8p+7 (old). All accesses wave-uniform
    // slot + lane-contiguous columns -> conflict-free.
    __shared__ float pub[2][32][H];   // 64 KiB
    const int tid = threadIdx.x, b = blockIdx.x;
    const int p = tid >> 6, lane = tid & 63;
    const int h0 = lane * 4;

    __half2 wpk[WPT];
#pragma unroll
    for (int i = 0; i < WPT; ++i) wpk[i] = g_PK[i * 1024 + tid];

    float a[8][4];
#pragma unroll
    for (int r = 0; r < 8; ++r)
#pragma unroll
        for (int j = 0; j < 4; ++j) a[r][j] = 0.f;
    if (p == 0) {
        const float4 pr = *(const float4*)&g_pre[b * H + h0];
        a[0][0] = pr.x; a[0][1] = pr.y; a[0][2] = pr.z; a[0][3] = pr.w;
    }

    int buf = 0;
    for (int it = 0; it < ITERS; ++it) {
        *(float4*)&pub[buf][2 * p][h0]     = make_float4(a[0][0], a[0][1], a[0][2], a[0][3]);
        *(float4*)&pub[buf][2 * p + 1][h0] = make_float4(a[7][0], a[7][1], a[7][2], a[7][3]);
        __syncthreads();
        const float4 hl = (p == 0)  ? make_float4(0.f, 0.f, 0.f, 0.f)
                                    : *(const float4*)&pub[buf][2 * p - 1][h0];
        const float4 hr = (p == 15) ? make_float4(0.f, 0.f, 0.f, 0.f)
                                    : *(const float4*)&pub[buf][2 * p + 2][h0];
        float pm[4] = {hl.x, hl.y, hl.z, hl.w};   // old act row w-1
#pragma unroll
        for (int rw = 0; rw < 8; ++rw) {
            const float c0 = a[rw][0], c1 = a[rw][1], c2 = a[rw][2], c3 = a[rw][3];
            float nx0, nx1, nx2, nx3;             // old act row w+1
            if (rw == 7) { nx0 = hr.x; nx1 = hr.y; nx2 = hr.z; nx3 = hr.w; }
            else { nx0 = a[rw + 1][0]; nx1 = a[rw + 1][1]; nx2 = a[rw + 1][2]; nx3 = a[rw + 1][3]; }
            const float lm = __shfl_up(c3, 1, 64);    // old act[w][h0-1]; *0 at lane 0
            const float rp = __shfl_down(c0, 1, 64);  // old act[w][h0+4]; *0 at lane 63
            const float2 va = __half22float2(wpk[32 + rw * 3 + 0]);
            const float2 vbv = __half22float2(wpk[32 + rw * 3 + 1]);
            const float2 vc = __half22float2(wpk[32 + rw * 3 + 2]);
            const float vv0 = va.x, vv1 = va.y, vv2 = vbv.x, vv3 = vbv.y, vv4 = vc.x;
            const float2 bsa = __half22float2(wpk[56 + rw * 2 + 0]);
            const float2 bsb = __half22float2(wpk[56 + rw * 2 + 1]);
            const float2 h0w = __half22float2(wpk[rw * 4 + 0]);
            const float2 h1w = __half22float2(wpk[rw * 4 + 1]);
            const float2 h2w = __half22float2(wpk[rw * 4 + 2]);
            const float2 h3w = __half22float2(wpk[rw * 4 + 3]);
            const float x0 = bsa.x + h0w.x * pm[0] + h0w.y * nx0 + vv0 * lm + vv1 * c1;
            const float x1 = bsa.y + h1w.x * pm[1] + h1w.y * nx1 + vv1 * c0 + vv2 * c2;
            const float x2 = bsb.x + h2w.x * pm[2] + h2w.y * nx2 + vv2 * c1 + vv3 * c3;
            const float x3 = bsb.y + h3w.x * pm[3] + h3w.y * nx3 + vv3 * c2 + vv4 * rp;
            a[rw][0] = 1.f / (1.f + __expf(-x0));
            a[rw][1] = 1.f / (1.f + __expf(-x1));
            a[rw][2] = 1.f / (1.f + __expf(-x2));
            a[rw][3] = 1.f / (1.f + __expf(-x3));
            pm[0] = c0; pm[1] = c1; pm[2] = c2; pm[3] = c3;
        }
        buf ^= 1;
    }

    // out[b] = act[w=126] @ w_out + b_out ; w=126 is group p=15, rw=6
    if (p == 15) {
        float acc[NC];
#pragma unroll
        for (int c = 0; c < NC; ++c) acc[c] = 0.f;
#pragma unroll
        for (int j = 0; j < 4; ++j) {
            const float av = a[6][j];
            const float* wr = w_out + (h0 + j) * NC;
#pragma unroll
            for (int c = 0; c < NC; ++c) acc[c] += av * wr[c];
        }
#pragma unroll
        for (int off = 32; off >= 1; off >>= 1)
#pragma unroll
            for (int c = 0; c < NC; ++c) acc[c] += __shfl_down(acc[c], off, 64);
        if (lane == 0) {
#pragma unroll
            for (int c = 0; c < NC; ++c) out[b * NC + c] = acc[c] + b_out[c];
        }
    }
}

extern "C" void kernel_launch(void* const* d_in, const int* in_sizes, int n_in,
                              void* d_out, int out_size, void* d_ws, size_t ws_size,
                              hipStream_t stream) {
    const float* x     = (const float*)d_in[0];
    const float* w_pre = (const float*)d_in[1];
    const float* b_pre = (const float*)d_in[2];
    const float* hw    = (const float*)d_in[3];
    const float* vw    = (const float*)d_in[4];
    const float* hb    = (const float*)d_in[5];
    const float* vb    = (const float*)d_in[6];
    const float* w_out = (const float*)d_in[7];
    const float* b_out = (const float*)d_in[8];
    float* out = (float*)d_out;

    hipLaunchKernelGGL(build_pack, dim3(1), dim3(1024), 0, stream, hw, vw, hb, vb);
    hipLaunchKernelGGL(pre_gemm, dim3(B), dim3(H), 0, stream, x, w_pre, b_pre);
    hipLaunchKernelGGL(grid_iter, dim3(B), dim3(1024), 0, stream, w_out, b_out, out);
}

// Round 3
// 296.078 us; speedup vs baseline: 2.7799x; 1.4167x over previous
//
#include <hip/hip_runtime.h>
#include <hip/hip_fp16.h>

constexpr int W = 128, H = 256, ITERS = 24, B = 256, K_IN = 784, NC = 10;
constexpr int NHW = 18;                 // hw words per thread (9 rows x 2 half2)
constexpr int NVW = 24;                 // vw words per thread (8 rows x 3 half2)
constexpr int NWPK = NHW + NVW;         // 42 register-resident weight words
constexpr int NB = 16;                  // bias half2 words per thread (LDS-resident)
constexpr int PUB_WORDS = 2 * 32 * H;   // 16384 floats = 64 KiB
constexpr int LDS_BYTES = PUB_WORDS * 4 + NB * 1024 * 4;   // 131072

// Rebuilt fully on every launch; no cross-call state is read before write.
__device__ __half2 g_PK[NWPK * 1024];   // [word][tid]
__device__ __half2 g_BIAS[NB * 1024];   // [word][tid]
__device__ float g_pre[B * H];

// Thread mapping (shared by build_pack and grid_iter):
//   p = tid>>6, lane = tid&63; rows w = 8p..8p+7, cols h = 4*lane..4*lane+3.
// g_PK words per thread t:
//   [i*2+jj]        i=0..8: half2( hw[8p-1+i][h0+2jj], hw[8p-1+i][h0+2jj+1] ), 0 if row invalid
//   [18+rw*3+k]     k=0..2: half2( vwv[rw][2k], vwv[rw][2k+1] ), vwv[rw][m]=vw[8p+rw][h0-1+m] (m<=4), 0 if invalid
// g_BIAS words: [rw*2+jj] = half2(biassum(8p+rw, h0+2jj), biassum(8p+rw, h0+2jj+1))
__global__ void build_pack(const float* __restrict__ hw, const float* __restrict__ vw,
                           const float* __restrict__ hbp, const float* __restrict__ vbp) {
    const int t = blockIdx.x * 64 + threadIdx.x;   // 16 blocks x 64
    const int p = t >> 6, lane = t & 63;
    const int w8 = p * 8, h0 = lane * 4;

    for (int i = 0; i < 9; ++i) {
        const int wp = w8 - 1 + i;                 // hw row index, valid 0..W-2
        for (int jj = 0; jj < 2; ++jj) {
            float v0 = 0.f, v1 = 0.f;
            if (wp >= 0 && wp <= W - 2) {
                v0 = hw[wp * H + h0 + 2 * jj];
                v1 = hw[wp * H + h0 + 2 * jj + 1];
            }
            g_PK[(i * 2 + jj) * 1024 + t] = __floats2half2_rn(v0, v1);
        }
    }
    for (int rw = 0; rw < 8; ++rw) {
        const int w = w8 + rw;
        for (int k = 0; k < 3; ++k) {
            float s[2] = {0.f, 0.f};
            for (int mm = 0; mm < 2; ++mm) {
                const int m = 2 * k + mm;
                if (m <= 4) {
                    const int hp = h0 - 1 + m;     // vw col index, valid 0..H-2
                    if (hp >= 0 && hp <= H - 2) s[mm] = vw[w * (H - 1) + hp];
                }
            }
            g_PK[(NHW + rw * 3 + k) * 1024 + t] = __floats2half2_rn(s[0], s[1]);
        }
    }
    for (int rw = 0; rw < 8; ++rw) {
        const int w = w8 + rw;
        for (int jj = 0; jj < 2; ++jj) {
            float s[2];
            for (int mm = 0; mm < 2; ++mm) {
                const int h = h0 + 2 * jj + mm;
                float v = 0.f;
                if (w >= 1)     v += hbp[(w - 1) * H + h];
                if (w <= W - 2) v += hbp[w * H + h];
                if (h >= 1)     v += vbp[w * (H - 1) + h - 1];
                if (h <= H - 2) v += vbp[w * (H - 1) + h];
                s[mm] = v;
            }
            g_BIAS[(rw * 2 + jj) * 1024 + t] = __floats2half2_rn(s[0], s[1]);
        }
    }
}

__global__ void pre_gemm(const float* __restrict__ x, const float* __restrict__ w_pre,
                         const float* __restrict__ b_pre) {
    __shared__ float xs[K_IN];
    const int b = blockIdx.x, j = threadIdx.x;     // 256 x 256
    for (int k = j; k < K_IN; k += 256) xs[k] = x[b * K_IN + k];
    __syncthreads();
    float acc = b_pre[j];
#pragma unroll 16
    for (int k = 0; k < K_IN; ++k) acc += xs[k] * w_pre[k * H + j];
    g_pre[b * H + j] = acc;
}

__global__ void __launch_bounds__(1024)
__attribute__((amdgpu_waves_per_eu(4, 4)))
grid_iter(const float* __restrict__ w_out, const float* __restrict__ b_out,
          float* __restrict__ out) {
    extern __shared__ unsigned char smem[];
    float* pub = (float*)smem;                           // [2][32][H] doubles-buffered halo
    __half2* biasl = (__half2*)(smem + PUB_WORDS * 4);   // [NB][1024]

    const int tid = threadIdx.x, b = blockIdx.x;
    const int p = tid >> 6, lane = tid & 63;
    const int h0 = lane * 4;

    __half2 wpk[NWPK];
#pragma unroll
    for (int i = 0; i < NWPK; ++i) wpk[i] = g_PK[i * 1024 + tid];
#pragma unroll
    for (int i = 0; i < NB; ++i) biasl[i * 1024 + tid] = g_BIAS[i * 1024 + tid];

    float a[8][4];
#pragma unroll
    for (int r = 0; r < 8; ++r)
#pragma unroll
        for (int j = 0; j < 4; ++j) a[r][j] = 0.f;
    if (p == 0) {
        const float4 pr = *(const float4*)&g_pre[b * H + h0];
        a[0][0] = pr.x; a[0][1] = pr.y; a[0][2] = pr.z; a[0][3] = pr.w;
    }

    int buf = 0;
    for (int it = 0; it < ITERS; ++it) {
        *(float4*)&pub[(buf * 32 + 2 * p) * H + h0] =
            make_float4(a[0][0], a[0][1], a[0][2], a[0][3]);
        *(float4*)&pub[(buf * 32 + 2 * p + 1) * H + h0] =
            make_float4(a[7][0], a[7][1], a[7][2], a[7][3]);
        __syncthreads();
        const float4 hl = (p == 0)  ? make_float4(0.f, 0.f, 0.f, 0.f)
                                    : *(const float4*)&pub[(buf * 32 + 2 * p - 1) * H + h0];
        const float4 hr = (p == 15) ? make_float4(0.f, 0.f, 0.f, 0.f)
                                    : *(const float4*)&pub[(buf * 32 + 2 * p + 2) * H + h0];
        float pm0 = hl.x, pm1 = hl.y, pm2 = hl.z, pm3 = hl.w;   // old act row w-1
#pragma unroll
        for (int rw = 0; rw < 8; ++rw) {
            const float c0 = a[rw][0], c1 = a[rw][1], c2 = a[rw][2], c3 = a[rw][3];
            float nx0, nx1, nx2, nx3;                            // old act row w+1
            if (rw == 7) { nx0 = hr.x; nx1 = hr.y; nx2 = hr.z; nx3 = hr.w; }
            else { nx0 = a[rw + 1][0]; nx1 = a[rw + 1][1]; nx2 = a[rw + 1][2]; nx3 = a[rw + 1][3]; }
            const float lm = __shfl_up(c3, 1, 64);    // old act[w][h0-1]; coeff 0 at lane 0
            const float rp = __shfl_down(c0, 1, 64);  // old act[w][h0+4]; coeff 0 at lane 63
            const float2 wL01 = __half22float2(wpk[rw * 2 + 0]);
            const float2 wL23 = __half22float2(wpk[rw * 2 + 1]);
            const float2 wR01 = __half22float2(wpk[(rw + 1) * 2 + 0]);
            const float2 wR23 = __half22float2(wpk[(rw + 1) * 2 + 1]);
            const float2 v01 = __half22float2(wpk[NHW + rw * 3 + 0]);
            const float2 v23 = __half22float2(wpk[NHW + rw * 3 + 1]);
            const float2 v4x = __half22float2(wpk[NHW + rw * 3 + 2]);
            const float2 b01 = __half22float2(biasl[(rw * 2 + 0) * 1024 + tid]);
            const float2 b23 = __half22float2(biasl[(rw * 2 + 1) * 1024 + tid]);
            const float x0 = b01.x + wL01.x * pm0 + wR01.x * nx0 + v01.x * lm + v01.y * c1;
            const float x1 = b01.y + wL01.y * pm1 + wR01.y * nx1 + v01.y * c0 + v23.x * c2;
            const float x2 = b23.x + wL23.x * pm2 + wR23.x * nx2 + v23.x * c1 + v23.y * c3;
            const float x3 = b23.y + wL23.y * pm3 + wR23.y * nx3 + v23.y * c2 + v4x.x * rp;
            a[rw][0] = __builtin_amdgcn_rcpf(1.f + __expf(-x0));
            a[rw][1] = __builtin_amdgcn_rcpf(1.f + __expf(-x1));
            a[rw][2] = __builtin_amdgcn_rcpf(1.f + __expf(-x2));
            a[rw][3] = __builtin_amdgcn_rcpf(1.f + __expf(-x3));
            pm0 = c0; pm1 = c1; pm2 = c2; pm3 = c3;
        }
        buf ^= 1;
    }

    // out[b] = act[w=126] @ w_out + b_out ; w=126 is p=15, rw=6
    if (p == 15) {
        float acc[NC];
#pragma unroll
        for (int c = 0; c < NC; ++c) acc[c] = 0.f;
#pragma unroll
        for (int j = 0; j < 4; ++j) {
            const float av = a[6][j];
            const float* wr = w_out + (h0 + j) * NC;
#pragma unroll
            for (int c = 0; c < NC; ++c) acc[c] += av * wr[c];
        }
#pragma unroll
        for (int off = 32; off >= 1; off >>= 1)
#pragma unroll
            for (int c = 0; c < NC; ++c) acc[c] += __shfl_down(acc[c], off, 64);
        if (lane == 0) {
#pragma unroll
            for (int c = 0; c < NC; ++c) out[b * NC + c] = acc[c] + b_out[c];
        }
    }
}

extern "C" void kernel_launch(void* const* d_in, const int* in_sizes, int n_in,
                              void* d_out, int out_size, void* d_ws, size_t ws_size,
                              hipStream_t stream) {
    const float* x     = (const float*)d_in[0];
    const float* w_pre = (const float*)d_in[1];
    const float* b_pre = (const float*)d_in[2];
    const float* hw    = (const float*)d_in[3];
    const float* vw    = (const float*)d_in[4];
    const float* hb    = (const float*)d_in[5];
    const float* vb    = (const float*)d_in[6];
    const float* w_out = (const float*)d_in[7];
    const float* b_out = (const float*)d_in[8];
    float* out = (float*)d_out;

    (void)hipFuncSetAttribute((const void*)grid_iter,
                              hipFuncAttributeMaxDynamicSharedMemorySize, LDS_BYTES);

    hipLaunchKernelGGL(build_pack, dim3(16), dim3(64), 0, stream, hw, vw, hb, vb);
    hipLaunchKernelGGL(pre_gemm, dim3(B), dim3(H), 0, stream, x, w_pre, b_pre);
    hipLaunchKernelGGL(grid_iter, dim3(B), dim3(1024), LDS_BYTES, stream, w_out, b_out, out);
}

// Round 4
// 122.922 us; speedup vs baseline: 6.6957x; 2.4087x over previous
//
#include <hip/hip_runtime.h>
#include <hip/hip_fp16.h>

constexpr int W = 128, H = 256, ITERS = 24, B = 256, K_IN = 784, NC = 10;
constexpr int NHW = 18;                          // hw half2 words per thread (registers)
constexpr int VWS_HALFS = 128 * 260;             // V[w][m], stride 260 for 8B row alignment
constexpr int BIA_HALFS = 128 * 256;             // bias sum per cell
constexpr int WB_HALFS = VWS_HALFS + BIA_HALFS;  // 66048
constexpr int WB_BYTES = WB_HALFS * 2;           // 132096
constexpr int LDS_BYTES = WB_BYTES + 32 * 256 * 2;  // +16KB pub = 148480

// Rebuilt fully on every launch; no cross-call state read before write.
__device__ __align__(16) __half g_WB[WB_HALFS];  // [vws | bias]
__device__ __half2 g_PK[NHW * 1024];             // hw words, [word][tid]
__device__ float g_pre[B * H];

// Thread map (build_pack and grid_iter must agree):
//   p = tid>>6 (wave), lane = tid&63; rows w = 8p..8p+7, cols h = 4*lane..4*lane+3.
// g_PK[i*2+jj][t], i=0..8: half2( hwS(8p-1+i, h0+2jj), hwS(.., h0+2jj+1) ),
//   hwS(wp,h) = hw[wp*H+h] if 0<=wp<=126 else 0.  wL(rw)=words 2rw..2rw+1, wR=2rw+2..2rw+3.
// vws: V[w][m] = vw[w*255 + m-1] if 1<=m<=255 else 0 (aD coeff at h=m; aU coeff at h = V[w][h+1]).
// bias[w*256+h] = masked hbL+hbR+vbD+vbU.
__global__ void build_pack(const float* __restrict__ hw, const float* __restrict__ vw,
                           const float* __restrict__ hbp, const float* __restrict__ vbp) {
    const int idx = blockIdx.x * blockDim.x + threadIdx.x;
    const int nthr = gridDim.x * blockDim.x;

    for (int t = idx; t < 1024; t += nthr) {
        const int p = t >> 6, lane = t & 63;
        const int w8 = p * 8, h0 = lane * 4;
        for (int i = 0; i < 9; ++i) {
            const int wp = w8 - 1 + i;
            for (int jj = 0; jj < 2; ++jj) {
                float v0 = 0.f, v1 = 0.f;
                if (wp >= 0 && wp <= W - 2) {
                    v0 = hw[wp * H + h0 + 2 * jj];
                    v1 = hw[wp * H + h0 + 2 * jj + 1];
                }
                g_PK[(i * 2 + jj) * 1024 + t] = __floats2half2_rn(v0, v1);
            }
        }
    }
    for (int i = idx; i < VWS_HALFS; i += nthr) {
        const int w = i / 260, m = i % 260;
        float v = (m >= 1 && m <= H - 1) ? vw[w * (H - 1) + m - 1] : 0.f;
        g_WB[i] = __float2half(v);
    }
    for (int i = idx; i < BIA_HALFS; i += nthr) {
        const int w = i >> 8, h = i & 255;
        float v = 0.f;
        if (w >= 1)     v += hbp[(w - 1) * H + h];
        if (w <= W - 2) v += hbp[w * H + h];
        if (h >= 1)     v += vbp[w * (H - 1) + h - 1];
        if (h <= H - 2) v += vbp[w * (H - 1) + h];
        g_WB[VWS_HALFS + i] = __float2half(v);
    }
}

__global__ void pre_gemm(const float* __restrict__ x, const float* __restrict__ w_pre,
                         const float* __restrict__ b_pre) {
    __shared__ float xs[K_IN];
    const int b = blockIdx.x, j = threadIdx.x;     // 256 x 256
    for (int k = j; k < K_IN; k += 256) xs[k] = x[b * K_IN + k];
    __syncthreads();
    float acc = b_pre[j];
#pragma unroll 16
    for (int k = 0; k < K_IN; ++k) acc += xs[k] * w_pre[k * H + j];
    g_pre[b * H + j] = acc;
}

__global__ void __launch_bounds__(1024)
__attribute__((amdgpu_waves_per_eu(4, 4), amdgpu_num_vgpr(128)))
grid_iter(const float* __restrict__ w_out, const float* __restrict__ b_out,
          float* __restrict__ out) {
    extern __shared__ unsigned char smem[];
    __half* vws  = (__half*)smem;                        // [128][260]
    __half* bia  = (__half*)(smem + VWS_HALFS * 2);      // [128][256]
    __half* pubh = (__half*)(smem + WB_BYTES);           // [32][256] single-buffer

    const int tid = threadIdx.x, b = blockIdx.x;
    const int p = tid >> 6, lane = tid & 63;
    const int h0 = lane * 4;

    {   // stage vws+bias into LDS (coalesced 16B chunks; 8256 = 8*1024 + 64)
        const uint4* src = (const uint4*)g_WB;
        uint4* dst = (uint4*)smem;
        for (int i = tid; i < WB_BYTES / 16; i += 1024) dst[i] = src[i];
    }
    __half2 hwreg[NHW];
#pragma unroll
    for (int i = 0; i < NHW; ++i) hwreg[i] = g_PK[i * 1024 + tid];

    __half2 a2[16];   // act rows rw=0..7, 2 words each (4 fp16 cols)
#pragma unroll
    for (int i = 0; i < 16; ++i) a2[i] = __floats2half2_rn(0.f, 0.f);
    if (p == 0) {
        const float4 pr = *(const float4*)&g_pre[b * H + h0];
        a2[0] = __floats2half2_rn(pr.x, pr.y);
        a2[1] = __floats2half2_rn(pr.z, pr.w);
    }
    __syncthreads();

    for (int it = 0; it < ITERS; ++it) {
        // publish OLD boundary rows (group rows 0 and 7)
        *(__half2*)(pubh + (2 * p) * 256 + h0)         = a2[0];
        *(__half2*)(pubh + (2 * p) * 256 + h0 + 2)     = a2[1];
        *(__half2*)(pubh + (2 * p + 1) * 256 + h0)     = a2[14];
        *(__half2*)(pubh + (2 * p + 1) * 256 + h0 + 2) = a2[15];
        __syncthreads();

        float pm0, pm1, pm2, pm3;     // old act row w-1 (starts as left halo)
        if (p == 0) { pm0 = pm1 = pm2 = pm3 = 0.f; }
        else {
            const float2 u0 = __half22float2(*(const __half2*)(pubh + (2 * p - 1) * 256 + h0));
            const float2 u1 = __half22float2(*(const __half2*)(pubh + (2 * p - 1) * 256 + h0 + 2));
            pm0 = u0.x; pm1 = u0.y; pm2 = u1.x; pm3 = u1.y;
        }
        float hr0, hr1, hr2, hr3;     // right halo (old row 8p+8)
        if (p == 15) { hr0 = hr1 = hr2 = hr3 = 0.f; }
        else {
            const float2 u0 = __half22float2(*(const __half2*)(pubh + (2 * p + 2) * 256 + h0));
            const float2 u1 = __half22float2(*(const __half2*)(pubh + (2 * p + 2) * 256 + h0 + 2));
            hr0 = u0.x; hr1 = u0.y; hr2 = u1.x; hr3 = u1.y;
        }
        float c0, c1, c2, c3;         // old act of current row (carried down)
        {
            const float2 u0 = __half22float2(a2[0]), u1 = __half22float2(a2[1]);
            c0 = u0.x; c1 = u0.y; c2 = u1.x; c3 = u1.y;
        }
#pragma unroll
        for (int rw = 0; rw < 8; ++rw) {
            const int w = 8 * p + rw;
            float nx0, nx1, nx2, nx3;                    // old act row w+1
            if (rw == 7) { nx0 = hr0; nx1 = hr1; nx2 = hr2; nx3 = hr3; }
            else {
                const float2 u0 = __half22float2(a2[2 * rw + 2]);
                const float2 u1 = __half22float2(a2[2 * rw + 3]);
                nx0 = u0.x; nx1 = u0.y; nx2 = u1.x; nx3 = u1.y;
            }
            const float lm = __shfl_up(c3, 1, 64);       // old act[w][h0-1]; coeff 0 at lane 0
            float rp = __shfl_down(c0, 1, 64);           // old act[w][h0+4]

            const __half2* vp = (const __half2*)(vws + w * 260 + h0);   // 8B-aligned
            const float2 vA = __half22float2(vp[0]);     // V[h0], V[h0+1]
            const float2 vB = __half22float2(vp[1]);     // V[h0+2], V[h0+3]
            float v4 = __shfl_down(vA.x, 1, 64);         // V[h0+4]
            v4 = (lane == 63) ? 0.f : v4;                // V[256] pad

            const __half2* bp = (const __half2*)(bia + w * 256 + h0);
            const float2 bA = __half22float2(bp[0]);
            const float2 bB = __half22float2(bp[1]);

            const float2 wL01 = __half22float2(hwreg[2 * rw]);
            const float2 wL23 = __half22float2(hwreg[2 * rw + 1]);
            const float2 wR01 = __half22float2(hwreg[2 * rw + 2]);
            const float2 wR23 = __half22float2(hwreg[2 * rw + 3]);

            const float x0 = bA.x + wL01.x * pm0 + wR01.x * nx0 + vA.x * lm + vA.y * c1;
            const float x1 = bA.y + wL01.y * pm1 + wR01.y * nx1 + vA.y * c0 + vB.x * c2;
            const float x2 = bB.x + wL23.x * pm2 + wR23.x * nx2 + vB.x * c1 + vB.y * c3;
            const float x3 = bB.y + wL23.y * pm3 + wR23.y * nx3 + vB.y * c2 + v4 * rp;

            const float s0 = __builtin_amdgcn_rcpf(1.f + __expf(-x0));
            const float s1 = __builtin_amdgcn_rcpf(1.f + __expf(-x1));
            const float s2 = __builtin_amdgcn_rcpf(1.f + __expf(-x2));
            const float s3 = __builtin_amdgcn_rcpf(1.f + __expf(-x3));
            a2[2 * rw]     = __floats2half2_rn(s0, s1);
            a2[2 * rw + 1] = __floats2half2_rn(s2, s3);

            pm0 = c0; pm1 = c1; pm2 = c2; pm3 = c3;      // carry old values down
            c0 = nx0; c1 = nx1; c2 = nx2; c3 = nx3;
        }
        __syncthreads();   // all halo reads done before next iter's pub writes
    }

    // out[b] = act[w=126] @ w_out + b_out ; w=126 is p=15, rw=6 -> a2[12..13]
    if (p == 15) {
        const float2 u0 = __half22float2(a2[12]), u1 = __half22float2(a2[13]);
        const float av[4] = {u0.x, u0.y, u1.x, u1.y};
        float acc[NC];
#pragma unroll
        for (int c = 0; c < NC; ++c) acc[c] = 0.f;
#pragma unroll
        for (int j = 0; j < 4; ++j) {
            const float* wr = w_out + (h0 + j) * NC;
#pragma unroll
            for (int c = 0; c < NC; ++c) acc[c] += av[j] * wr[c];
        }
#pragma unroll
        for (int off = 32; off >= 1; off >>= 1)
#pragma unroll
            for (int c = 0; c < NC; ++c) acc[c] += __shfl_down(acc[c], off, 64);
        if (lane == 0) {
#pragma unroll
            for (int c = 0; c < NC; ++c) out[b * NC + c] = acc[c] + b_out[c];
        }
    }
}

extern "C" void kernel_launch(void* const* d_in, const int* in_sizes, int n_in,
                              void* d_out, int out_size, void* d_ws, size_t ws_size,
                              hipStream_t stream) {
    const float* x     = (const float*)d_in[0];
    const float* w_pre = (const float*)d_in[1];
    const float* b_pre = (const float*)d_in[2];
    const float* hw    = (const float*)d_in[3];
    const float* vw    = (const float*)d_in[4];
    const float* hb    = (const float*)d_in[5];
    const float* vb    = (const float*)d_in[6];
    const float* w_out = (const float*)d_in[7];
    const float* b_out = (const float*)d_in[8];
    float* out = (float*)d_out;

    (void)hipFuncSetAttribute((const void*)grid_iter,
                              hipFuncAttributeMaxDynamicSharedMemorySize, LDS_BYTES);

    hipLaunchKernelGGL(build_pack, dim3(32), dim3(256), 0, stream, hw, vw, hb, vb);
    hipLaunchKernelGGL(pre_gemm, dim3(B), dim3(H), 0, stream, x, w_pre, b_pre);
    hipLaunchKernelGGL(grid_iter, dim3(B), dim3(1024), LDS_BYTES, stream, w_out, b_out, out);
}

// Round 5
// 88.432 us; speedup vs baseline: 9.3072x; 1.3900x over previous
//
#include <hip/hip_runtime.h>
#include <hip/hip_fp16.h>

constexpr int W = 128, H = 256, ITERS = 24, B = 256, K_IN = 784, NC = 10;
constexpr int NPK = 66;   // per-thread packed half2 weight words (registers)
constexpr float NLOG2E = -1.4426950408889634f;   // fold sigmoid's exp->exp2 into weights

// Rebuilt fully on every launch; no cross-call state read before write.
__device__ __half2 g_PKW[NPK * 1024];   // [word][tid]
__device__ float g_pre[B * H];

// Thread map (build_pack and grid_iter must agree):
//   p = tid>>6 (wave), lane = tid&63; rows w = 8p..8p+7, cols h = 4*lane..4*lane+3.
// All values pre-scaled by NLOG2E. With V(w,m) = vw[w*255+m-1] for 1<=m<=255 else 0,
// hwS(wp,h) = hw[wp*256+h] for 0<=wp<=126 else 0:
//   word 2i+jj (i=0..8, jj=0..1): ( hwS(8p-1+i, h0+2jj), hwS(8p-1+i, h0+2jj+1) )
//   18+rw: vA=(V(w,h0),V(w,h0+1))   26+rw: vB=(V(w,h0+2),V(w,h0+3))
//   34+rw: vS=(V(w,h0+1),V(w,h0+2)) 42+rw: vT=(V(w,h0+3),V(w,h0+4))
//   50+2rw+jj: bias-sum pairs
__global__ void build_pack(const float* __restrict__ hw, const float* __restrict__ vw,
                           const float* __restrict__ hbp, const float* __restrict__ vbp) {
    const int t = blockIdx.x * blockDim.x + threadIdx.x;   // 16 x 64 = 1024
    if (t >= 1024) return;
    const int p = t >> 6, lane = t & 63;
    const int w8 = p * 8, h0 = lane * 4;

    auto HWS = [&](int wp, int h) -> float {
        return (wp >= 0 && wp <= W - 2) ? hw[wp * H + h] : 0.f;
    };
    auto VV = [&](int w, int m) -> float {
        return (m >= 1 && m <= H - 1) ? vw[w * (H - 1) + m - 1] : 0.f;
    };

    for (int i = 0; i < 9; ++i)
        for (int jj = 0; jj < 2; ++jj) {
            const int wp = w8 - 1 + i, h = h0 + 2 * jj;
            g_PKW[(i * 2 + jj) * 1024 + t] =
                __floats2half2_rn(NLOG2E * HWS(wp, h), NLOG2E * HWS(wp, h + 1));
        }
    for (int rw = 0; rw < 8; ++rw) {
        const int w = w8 + rw;
        g_PKW[(18 + rw) * 1024 + t] =
            __floats2half2_rn(NLOG2E * VV(w, h0), NLOG2E * VV(w, h0 + 1));
        g_PKW[(26 + rw) * 1024 + t] =
            __floats2half2_rn(NLOG2E * VV(w, h0 + 2), NLOG2E * VV(w, h0 + 3));
        g_PKW[(34 + rw) * 1024 + t] =
            __floats2half2_rn(NLOG2E * VV(w, h0 + 1), NLOG2E * VV(w, h0 + 2));
        g_PKW[(42 + rw) * 1024 + t] =
            __floats2half2_rn(NLOG2E * VV(w, h0 + 3), NLOG2E * VV(w, h0 + 4));
        for (int jj = 0; jj < 2; ++jj) {
            float s[2];
            for (int mm = 0; mm < 2; ++mm) {
                const int h = h0 + 2 * jj + mm;
                float v = 0.f;
                if (w >= 1)     v += hbp[(w - 1) * H + h];
                if (w <= W - 2) v += hbp[w * H + h];
                if (h >= 1)     v += vbp[w * (H - 1) + h - 1];
                if (h <= H - 2) v += vbp[w * (H - 1) + h];
                s[mm] = NLOG2E * v;
            }
            g_PKW[(50 + rw * 2 + jj) * 1024 + t] = __floats2half2_rn(s[0], s[1]);
        }
    }
}

__global__ void pre_gemm(const float* __restrict__ x, const float* __restrict__ w_pre,
                         const float* __restrict__ b_pre) {
    __shared__ float xs[K_IN];
    const int b = blockIdx.x, j = threadIdx.x;     // 256 x 256
    for (int k = j; k < K_IN; k += 256) xs[k] = x[b * K_IN + k];
    __syncthreads();
    float acc = b_pre[j];
#pragma unroll 16
    for (int k = 0; k < K_IN; ++k) acc += xs[k] * w_pre[k * H + j];
    g_pre[b * H + j] = acc;
}

__device__ __forceinline__ unsigned h2u(__half2 v) { return __builtin_bit_cast(unsigned, v); }
__device__ __forceinline__ __half2 u2h(unsigned v) { return __builtin_bit_cast(__half2, v); }

__global__ void __launch_bounds__(1024, 4)
grid_iter(const float* __restrict__ w_out, const float* __restrict__ b_out,
          float* __restrict__ out) {
    // Halo exchange only: rows 1..32 live, rows 0 & 33 permanent zeros. Double-buffered.
    __shared__ __half pub[2][34][256];   // 34816 B

    const int tid = threadIdx.x, b = blockIdx.x;
    const int p = tid >> 6, lane = tid & 63;
    const int h0 = lane * 4;

    __half2 pk[NPK];
#pragma unroll
    for (int i = 0; i < NPK; ++i) pk[i] = g_PKW[i * 1024 + tid];

    {   // zero the 4 border rows (2 buffers x rows {0,33}); one half per thread
        const int bsel = tid >> 9, rsel = (tid >> 8) & 1, col = tid & 255;
        pub[bsel][rsel ? 33 : 0][col] = __float2half(0.f);
    }

    __half2 a2[16];   // act rows rw=0..7, 2 half2 each (cols h0..h0+3)
#pragma unroll
    for (int i = 0; i < 16; ++i) a2[i] = __floats2half2_rn(0.f, 0.f);
    if (p == 0) {
        const float4 pr = *(const float4*)&g_pre[b * H + h0];
        a2[0] = __floats2half2_rn(pr.x, pr.y);
        a2[1] = __floats2half2_rn(pr.z, pr.w);
    }
    const __half2 one2 = __floats2half2_rn(1.f, 1.f);
    __syncthreads();

#pragma unroll 2
    for (int it = 0; it < ITERS; ++it) {
        __half* pw = &pub[it & 1][0][0];
        // publish OLD boundary rows (group rows 0 and 7) as single b64 stores
        *(uint2*)(pw + (2 * p + 1) * 256 + h0) = make_uint2(h2u(a2[0]), h2u(a2[1]));
        *(uint2*)(pw + (2 * p + 2) * 256 + h0) = make_uint2(h2u(a2[14]), h2u(a2[15]));
        __syncthreads();
        const uint2 hlw = *(const uint2*)(pw + (2 * p) * 256 + h0);      // zeros at p==0
        const uint2 hrw = *(const uint2*)(pw + (2 * p + 3) * 256 + h0);  // zeros at p==15
        __half2 pm2a = u2h(hlw.x), pm2b = u2h(hlw.y);
        const __half2 hr2a = u2h(hrw.x), hr2b = u2h(hrw.y);

#pragma unroll
        for (int rw = 0; rw < 8; ++rw) {
            const __half2 c2a = a2[2 * rw], c2b = a2[2 * rw + 1];
            __half2 nx2a, nx2b;                 // old act row w+1
            if (rw == 7) { nx2a = hr2a; nx2b = hr2b; }
            else { nx2a = a2[2 * rw + 2]; nx2b = a2[2 * rw + 3]; }
            const unsigned lmw = __shfl_up(h2u(c2b), 1, 64);    // lane-1's (c2,c3)
            const unsigned rpw = __shfl_down(h2u(c2a), 1, 64);  // lane+1's (c0,c1)
            // garbage at lane edges is multiplied by 0-weights (V(w,0), V(w,256))
            const __half2 P1 = __halves2half2(__high2half(u2h(lmw)), __low2half(c2a));
            const __half2 P2 = __halves2half2(__high2half(c2a), __low2half(c2b));
            const __half2 P3 = __halves2half2(__high2half(c2b), __low2half(u2h(rpw)));

            __half2 ya = pk[50 + 2 * rw];
            ya = __hfma2(pk[2 * rw],     pm2a, ya);
            ya = __hfma2(pk[2 * rw + 2], nx2a, ya);
            ya = __hfma2(pk[18 + rw],    P1,   ya);
            ya = __hfma2(pk[34 + rw],    P2,   ya);
            __half2 yb = pk[51 + 2 * rw];
            yb = __hfma2(pk[2 * rw + 1], pm2b, yb);
            yb = __hfma2(pk[2 * rw + 3], nx2b, yb);
            yb = __hfma2(pk[26 + rw],    P2,   yb);
            yb = __hfma2(pk[42 + rw],    P3,   yb);

            // sigmoid(x) = 1/(1+2^y), y = -log2(e)*x (scale folded into weights)
            a2[2 * rw]     = h2rcp(__hadd2(one2, h2exp2(ya)));
            a2[2 * rw + 1] = h2rcp(__hadd2(one2, h2exp2(yb)));

            pm2a = c2a; pm2b = c2b;             // carry OLD row w down
        }
    }

    // out[b] = act[w=126] @ w_out + b_out ; w=126 is p=15, rw=6 -> a2[12..13]
    if (p == 15) {
        const float2 u0 = __half22float2(a2[12]), u1 = __half22float2(a2[13]);
        const float av[4] = {u0.x, u0.y, u1.x, u1.y};
        float acc[NC];
#pragma unroll
        for (int c = 0; c < NC; ++c) acc[c] = 0.f;
#pragma unroll
        for (int j = 0; j < 4; ++j) {
            const float* wr = w_out + (h0 + j) * NC;
#pragma unroll
            for (int c = 0; c < NC; ++c) acc[c] += av[j] * wr[c];
        }
#pragma unroll
        for (int off = 32; off >= 1; off >>= 1)
#pragma unroll
            for (int c = 0; c < NC; ++c) acc[c] += __shfl_down(acc[c], off, 64);
        if (lane == 0) {
#pragma unroll
            for (int c = 0; c < NC; ++c) out[b * NC + c] = acc[c] + b_out[c];
        }
    }
}

extern "C" void kernel_launch(void* const* d_in, const int* in_sizes, int n_in,
                              void* d_out, int out_size, void* d_ws, size_t ws_size,
                              hipStream_t stream) {
    const float* x     = (const float*)d_in[0];
    const float* w_pre = (const float*)d_in[1];
    const float* b_pre = (const float*)d_in[2];
    const float* hw    = (const float*)d_in[3];
    const float* vw    = (const float*)d_in[4];
    const float* hb    = (const float*)d_in[5];
    const float* vb    = (const float*)d_in[6];
    const float* w_out = (const float*)d_in[7];
    const float* b_out = (const float*)d_in[8];
    float* out = (float*)d_out;

    hipLaunchKernelGGL(build_pack, dim3(16), dim3(64), 0, stream, hw, vw, hb, vb);
    hipLaunchKernelGGL(pre_gemm, dim3(B), dim3(H), 0, stream, x, w_pre, b_pre);
    hipLaunchKernelGGL(grid_iter, dim3(B), dim3(1024), 0, stream, w_out, b_out, out);
}

// Round 6
// 82.887 us; speedup vs baseline: 9.9299x; 1.0669x over previous
//
#include <hip/hip_runtime.h>
#include <hip/hip_fp16.h>

constexpr int W = 128, H = 256, ITERS = 24, B = 256, K_IN = 784, NC = 10;
constexpr int NPK = 66;   // per-thread packed half2 weight words (registers)
constexpr float NLOG2E = -1.4426950408889634f;   // fold sigmoid exp->exp2 into weights

// Rebuilt fully on every launch; no cross-call state read before write.
__device__ __half2 g_PKW[NPK * 1024];   // [word][tid]

// Thread map (build_pack and grid_iter must agree):
//   p = tid>>6 (wave), lane = tid&63; rows w = 8p..8p+7, cols h = 4*lane..4*lane+3.
// All values pre-scaled by NLOG2E. With V(w,m) = vw[w*255+m-1] for 1<=m<=255 else 0,
// hwS(wp,h) = hw[wp*256+h] for 0<=wp<=126 else 0:
//   word 2i+jj (i=0..8, jj=0..1): ( hwS(8p-1+i, h0+2jj), hwS(8p-1+i, h0+2jj+1) )
//   18+rw: vA=(V(w,h0),V(w,h0+1))   26+rw: vB=(V(w,h0+2),V(w,h0+3))
//   34+rw: vS=(V(w,h0+1),V(w,h0+2)) 42+rw: vT=(V(w,h0+3),V(w,h0+4))
//   50+2rw+jj: bias-sum pairs
__global__ void build_pack(const float* __restrict__ hw, const float* __restrict__ vw,
                           const float* __restrict__ hbp, const float* __restrict__ vbp) {
    const int t = blockIdx.x * blockDim.x + threadIdx.x;   // 16 x 64 = 1024
    if (t >= 1024) return;
    const int p = t >> 6, lane = t & 63;
    const int w8 = p * 8, h0 = lane * 4;

    auto HWS = [&](int wp, int h) -> float {
        return (wp >= 0 && wp <= W - 2) ? hw[wp * H + h] : 0.f;
    };
    auto VV = [&](int w, int m) -> float {
        return (m >= 1 && m <= H - 1) ? vw[w * (H - 1) + m - 1] : 0.f;
    };

    for (int i = 0; i < 9; ++i)
        for (int jj = 0; jj < 2; ++jj) {
            const int wp = w8 - 1 + i, h = h0 + 2 * jj;
            g_PKW[(i * 2 + jj) * 1024 + t] =
                __floats2half2_rn(NLOG2E * HWS(wp, h), NLOG2E * HWS(wp, h + 1));
        }
    for (int rw = 0; rw < 8; ++rw) {
        const int w = w8 + rw;
        g_PKW[(18 + rw) * 1024 + t] =
            __floats2half2_rn(NLOG2E * VV(w, h0), NLOG2E * VV(w, h0 + 1));
        g_PKW[(26 + rw) * 1024 + t] =
            __floats2half2_rn(NLOG2E * VV(w, h0 + 2), NLOG2E * VV(w, h0 + 3));
        g_PKW[(34 + rw) * 1024 + t] =
            __floats2half2_rn(NLOG2E * VV(w, h0 + 1), NLOG2E * VV(w, h0 + 2));
        g_PKW[(42 + rw) * 1024 + t] =
            __floats2half2_rn(NLOG2E * VV(w, h0 + 3), NLOG2E * VV(w, h0 + 4));
        for (int jj = 0; jj < 2; ++jj) {
            float s[2];
            for (int mm = 0; mm < 2; ++mm) {
                const int h = h0 + 2 * jj + mm;
                float v = 0.f;
                if (w >= 1)     v += hbp[(w - 1) * H + h];
                if (w <= W - 2) v += hbp[w * H + h];
                if (h >= 1)     v += vbp[w * (H - 1) + h - 1];
                if (h <= H - 2) v += vbp[w * (H - 1) + h];
                s[mm] = NLOG2E * v;
            }
            g_PKW[(50 + rw * 2 + jj) * 1024 + t] = __floats2half2_rn(s[0], s[1]);
        }
    }
}

__device__ __forceinline__ unsigned h2u(__half2 v) { return __builtin_bit_cast(unsigned, v); }
__device__ __forceinline__ __half2 u2h(unsigned v) { return __builtin_bit_cast(__half2, v); }

// One row update. PA/PB (old row w-1) are lvalues, updated to this row's OLD value.
// NXA/NXB = old row w+1 (values). LU/RD hold lane-shifted packed edge halves.
#define ROWSTEP(RW, NXA, NXB, PA, PB)                                               \
    {                                                                               \
        const __half2 c2a = a2[2 * (RW)], c2b = a2[2 * (RW) + 1];                   \
        const unsigned P1 = __builtin_amdgcn_perm(h2u(c2a), LU[(RW) >> 1],          \
                              ((RW) & 1) ? 0x05040302u : 0x05040100u);              \
        const unsigned P2 = __builtin_amdgcn_perm(h2u(c2b), h2u(c2a), 0x05040302u); \
        const unsigned P3 = __builtin_amdgcn_perm(RD[(RW) >> 1], h2u(c2b),          \
                              ((RW) & 1) ? 0x07060302u : 0x05040302u);              \
        __half2 ya = pk[50 + 2 * (RW)];                                             \
        ya = __hfma2(pk[2 * (RW)],     PA,      ya);                                \
        ya = __hfma2(pk[2 * (RW) + 2], NXA,     ya);                                \
        ya = __hfma2(pk[18 + (RW)],    u2h(P1), ya);                                \
        ya = __hfma2(pk[34 + (RW)],    u2h(P2), ya);                                \
        __half2 yb = pk[51 + 2 * (RW)];                                             \
        yb = __hfma2(pk[2 * (RW) + 1], PB,      yb);                                \
        yb = __hfma2(pk[2 * (RW) + 3], NXB,     yb);                                \
        yb = __hfma2(pk[26 + (RW)],    u2h(P2), yb);                                \
        yb = __hfma2(pk[42 + (RW)],    u2h(P3), yb);                                \
        a2[2 * (RW)]     = h2rcp(__hadd2(one2, h2exp2(ya)));                        \
        a2[2 * (RW) + 1] = h2rcp(__hadd2(one2, h2exp2(yb)));                        \
        PA = c2a; PB = c2b;                                                         \
    }

__global__ void __launch_bounds__(1024, 4)
grid_iter(const float* __restrict__ x, const float* __restrict__ w_pre,
          const float* __restrict__ b_pre, const float* __restrict__ w_out,
          const float* __restrict__ b_out, float* __restrict__ out) {
    // 34816 B: first used as {xs[784] | part[4][256]} for the input GEMV,
    // then as the double-buffered halo pub[2][34][256] (rows 0/33 permanent zeros).
    __shared__ __align__(16) unsigned char smraw[2 * 34 * 256 * 2];
    float* xs   = (float*)smraw;
    float* part = (float*)(smraw + K_IN * 4);
    __half* pub = (__half*)smraw;

    const int tid = threadIdx.x, b = blockIdx.x;
    const int p = tid >> 6, lane = tid & 63;
    const int h0 = lane * 4;

    // ---- fused pre-GEMV: pre[j] = b_pre[j] + x[b,:] @ w_pre[:,j] ----
    for (int k = tid; k < K_IN; k += 1024) xs[k] = x[b * K_IN + k];
    __syncthreads();
    {
        const int j = tid & 255, chunk = tid >> 8;     // 4 chunks x 196
        const float* wp = w_pre + j;
        const int k0 = chunk * 196;
        float acc = 0.f;
#pragma unroll 4
        for (int k = 0; k < 196; ++k) acc += xs[k0 + k] * wp[(k0 + k) * H];
        part[chunk * 256 + j] = acc;
    }
    __syncthreads();
    float pr0 = 0.f, pr1 = 0.f, pr2 = 0.f, pr3 = 0.f;
    if (p == 0) {
        const float4 bp = *(const float4*)&b_pre[h0];
        pr0 = bp.x + part[h0]     + part[256 + h0]     + part[512 + h0]     + part[768 + h0];
        pr1 = bp.y + part[h0 + 1] + part[256 + h0 + 1] + part[512 + h0 + 1] + part[768 + h0 + 1];
        pr2 = bp.z + part[h0 + 2] + part[256 + h0 + 2] + part[512 + h0 + 2] + part[768 + h0 + 2];
        pr3 = bp.w + part[h0 + 3] + part[256 + h0 + 3] + part[512 + h0 + 3] + part[768 + h0 + 3];
    }
    __syncthreads();   // part fully consumed; smraw can be reused as pub

    // ---- weights into registers; zero pub border rows; init act ----
    __half2 pk[NPK];
#pragma unroll
    for (int i = 0; i < NPK; ++i) pk[i] = g_PKW[i * 1024 + tid];

    {   // rows 0 and 33 of both buffers; one half per thread
        const int bsel = tid >> 9, rsel = (tid >> 8) & 1, col = tid & 255;
        pub[(bsel * 34 + (rsel ? 33 : 0)) * 256 + col] = __float2half(0.f);
    }

    __half2 a2[16];   // act rows rw=0..7, 2 half2 each (cols h0..h0+3)
#pragma unroll
    for (int i = 0; i < 16; ++i) a2[i] = __floats2half2_rn(0.f, 0.f);
    if (p == 0) { a2[0] = __floats2half2_rn(pr0, pr1); a2[1] = __floats2half2_rn(pr2, pr3); }

    const __half2 one2 = __floats2half2_rn(1.f, 1.f);
    const int addr_up = (lane - 1) << 2;   // bpermute wraps mod 64; edge garbage hits 0-weights
    const int addr_dn = (lane + 1) << 2;
    __syncthreads();

#pragma unroll 2
    for (int it = 0; it < ITERS; ++it) {
        __half* pw = pub + (it & 1) * 34 * 256;
        // publish OLD boundary rows (group rows 0 and 7)
        *(uint2*)(pw + (2 * p + 1) * 256 + h0) = make_uint2(h2u(a2[0]), h2u(a2[1]));
        *(uint2*)(pw + (2 * p + 2) * 256 + h0) = make_uint2(h2u(a2[14]), h2u(a2[15]));

        // batched cross-lane edge exchange on OLD a2 (2 rows per bpermute)
        unsigned LU[4], RD[4];
#pragma unroll
        for (int k = 0; k < 4; ++k) {
            const unsigned uw = __builtin_amdgcn_perm(h2u(a2[4 * k + 3]), h2u(a2[4 * k + 1]), 0x07060302u);
            const unsigned dw = __builtin_amdgcn_perm(h2u(a2[4 * k + 2]), h2u(a2[4 * k]),     0x05040100u);
            LU[k] = __builtin_amdgcn_ds_bpermute(addr_up, uw);   // lane-1's (c3 row2k, c3 row2k+1)
            RD[k] = __builtin_amdgcn_ds_bpermute(addr_dn, dw);   // lane+1's (c0 row2k, c0 row2k+1)
        }
        const __half2 s1a = a2[2], s1b = a2[3];   // old row1 (overwritten before row0 needs it)
        __syncthreads();
        // issue halo loads early; consumed only by rows 0 and 7 at the end
        const uint2 hlw = *(const uint2*)(pw + (2 * p) * 256 + h0);      // zeros at p==0
        const uint2 hrw = *(const uint2*)(pw + (2 * p + 3) * 256 + h0);  // zeros at p==15

        __half2 pm2a = a2[0], pm2b = a2[1];       // old row0
        ROWSTEP(1, a2[4],  a2[5],  pm2a, pm2b);
        ROWSTEP(2, a2[6],  a2[7],  pm2a, pm2b);
        ROWSTEP(3, a2[8],  a2[9],  pm2a, pm2b);
        ROWSTEP(4, a2[10], a2[11], pm2a, pm2b);
        ROWSTEP(5, a2[12], a2[13], pm2a, pm2b);
        ROWSTEP(6, a2[14], a2[15], pm2a, pm2b);
        {   // row 0: pm = left halo, nx = saved old row1
            __half2 hl2a = u2h(hlw.x), hl2b = u2h(hlw.y);
            ROWSTEP(0, s1a, s1b, hl2a, hl2b);
        }
        // row 7: pm = old row6 (carried), nx = right halo
        ROWSTEP(7, u2h(hrw.x), u2h(hrw.y), pm2a, pm2b);
    }

    // out[b] = act[w=126] @ w_out + b_out ; w=126 is p=15, rw=6 -> a2[12..13]
    if (p == 15) {
        const float2 u0 = __half22float2(a2[12]), u1 = __half22float2(a2[13]);
        const float av[4] = {u0.x, u0.y, u1.x, u1.y};
        float acc[NC];
#pragma unroll
        for (int c = 0; c < NC; ++c) acc[c] = 0.f;
#pragma unroll
        for (int j = 0; j < 4; ++j) {
            const float* wr = w_out + (h0 + j) * NC;
#pragma unroll
            for (int c = 0; c < NC; ++c) acc[c] += av[j] * wr[c];
        }
#pragma unroll
        for (int off = 32; off >= 1; off >>= 1)
#pragma unroll
            for (int c = 0; c < NC; ++c) acc[c] += __shfl_down(acc[c], off, 64);
        if (lane == 0) {
#pragma unroll
            for (int c = 0; c < NC; ++c) out[b * NC + c] = acc[c] + b_out[c];
        }
    }
}

extern "C" void kernel_launch(void* const* d_in, const int* in_sizes, int n_in,
                              void* d_out, int out_size, void* d_ws, size_t ws_size,
                              hipStream_t stream) {
    const float* x     = (const float*)d_in[0];
    const float* w_pre = (const float*)d_in[1];
    const float* b_pre = (const float*)d_in[2];
    const float* hw    = (const float*)d_in[3];
    const float* vw    = (const float*)d_in[4];
    const float* hb    = (const float*)d_in[5];
    const float* vb    = (const float*)d_in[6];
    const float* w_out = (const float*)d_in[7];
    const float* b_out = (const float*)d_in[8];
    float* out = (float*)d_out;

    hipLaunchKernelGGL(build_pack, dim3(16), dim3(64), 0, stream, hw, vw, hb, vb);
    hipLaunchKernelGGL(grid_iter, dim3(B), dim3(1024), 0, stream,
                       x, w_pre, b_pre, w_out, b_out, out);
}